// Round 4
// baseline (14157.808 us; speedup 1.0000x reference)
//
#include <hip/hip_runtime.h>

// DA-RNN fused kernel — R4: 4 batches per block (256 blocks, ONE generation
// instead of four). Weights are batch-shared => same per-thread weight regs
// serve all 4 batches. E1 (decoder precomputed attn term) lives in REGISTERS
// (25 packed u32/thread); Xe (4x) lives in LDS (~158 KB of 160 KB/CU).
// x_tilde is streamed from global X (L3-resident) with cross-barrier prefetch.
// __launch_bounds__(1024,4): min 4 waves/EU => 128-VGPR cap (R3's missing 2nd
// arg gave a 64-cap and 108 MB of scratch traffic).

typedef unsigned int   u32;
typedef unsigned short u16;

#define T_ 100
#define C_ 32
#define NT 1024
#define BPB 4

__device__ __forceinline__ float bf2f(u16 u) {
  union { u32 i; float f; } v; v.i = ((u32)u) << 16; return v.f;
}
__device__ __forceinline__ u16 f2bf(float f) {
  union { float f; u32 i; } v; v.f = f;
  u32 r = v.i + 0x7fffu + ((v.i >> 16) & 1u);   // round-to-nearest-even
  return (u16)(r >> 16);
}
__device__ __forceinline__ void unpk(u32 p, float& lo, float& hi) {
  union { u32 i; float f; } a, b;
  a.i = p << 16; b.i = p & 0xffff0000u;
  lo = a.f; hi = b.f;
}
__device__ __forceinline__ u32 pk2(float a, float b) {
  return ((u32)f2bf(b) << 16) | (u32)f2bf(a);
}

typedef __attribute__((ext_vector_type(2))) __bf16 bf16x2;

#if __has_builtin(__builtin_amdgcn_fdot2_f32_bf16)
#define HAVE_DOT2 1
#else
#define HAVE_DOT2 0
#endif

__device__ __forceinline__ float dot2bf(u32 w, u32 x, float acc) {
#if HAVE_DOT2
  return __builtin_amdgcn_fdot2_f32_bf16(__builtin_bit_cast(bf16x2, w),
                                         __builtin_bit_cast(bf16x2, x),
                                         acc, false);
#else
  float a, b, c, d;
  unpk(w, a, b); unpk(x, c, d);
  return acc + a * c + b * d;
#endif
}

#if __has_builtin(__builtin_amdgcn_rcpf)
__device__ __forceinline__ float rcpf_(float x){ return __builtin_amdgcn_rcpf(x); }
#else
__device__ __forceinline__ float rcpf_(float x){ return 1.0f / x; }
#endif
__device__ __forceinline__ float sigm(float x){ return rcpf_(1.0f + __expf(-x)); }
__device__ __forceinline__ float tanh_(float x){
  return 1.0f - 2.0f * rcpf_(1.0f + __expf(2.0f * x));
}
// Poly tanh for S2 only: args provably small (|x| ~< 0.4); clamp for safety.
// Full-rate FMA vs quarter-rate transcendental.
__device__ __forceinline__ float ptanh(float x){
  x = fminf(1.0f, fmaxf(-1.0f, x));
  float x2 = x * x;
  float p  = fmaf(x2, 0.1333333f, -0.3333333f);
  return x * fmaf(x2, p, 1.0f);
}

__device__ __forceinline__ float wsum(float v){
  #pragma unroll
  for (int o = 32; o; o >>= 1) v += __shfl_xor(v, o, 64);
  return v;
}
__device__ __forceinline__ float wmax(float v){
  #pragma unroll
  for (int o = 32; o; o >>= 1) v = fmaxf(v, __shfl_xor(v, o, 64));
  return v;
}

__global__ void __launch_bounds__(NT, 4)
darnn_fused(const float* __restrict__ X,
            const float* __restrict__ eWih, const float* __restrict__ eWhh,
            const float* __restrict__ ebih, const float* __restrict__ ebhh,
            const float* __restrict__ eAw,  const float* __restrict__ eAb,
            const float* __restrict__ dW1,  const float* __restrict__ db1,
            const float* __restrict__ dW2,  const float* __restrict__ db2,
            const float* __restrict__ dWih, const float* __restrict__ dWhh,
            const float* __restrict__ dbih, const float* __restrict__ dbhh,
            const float* __restrict__ fcW,  const float* __restrict__ fcb,
            const float* __restrict__ fcfW, const float* __restrict__ fcfb,
            float* __restrict__ out)
{
  // LDS ~157.8 KB of 160 KB/CU (1 block/CU by construction)
  __shared__ __align__(16) u16   sXe[BPB][12800];   // X_enc bf16      102400 B
  __shared__ __align__(16) u16   sE1t[12800];       // E1 staging temp  25600 B
  __shared__ __align__(16) float sg[BPB][512];      // gates             8192 B
  __shared__ __align__(16) float sh[BPB][128];      // h/d fp32          2048 B
  __shared__ __align__(16) float sc[BPB][128];      // c fp32            2048 B
  __shared__ __align__(16) u16   shp[BPB][128];     // h/d bf16          1024 B
  __shared__ __align__(16) u16   scp[BPB][128];     // c bf16            1024 B
  __shared__ __align__(16) float su[BPB][128];      // alpha             2048 B
  __shared__ __align__(16) float spart[2048];       // u / ctx partials  8192 B
  __shared__ __align__(16) float sscore[BPB][128];  // scores -> beta    2048 B
  __shared__ __align__(16) float sctx[BPB][128];    // ctx               2048 B
  __shared__ __align__(16) u32   sxt[BPB][64];      // x_tilde packed    1024 B
  __shared__ float sredA[8];
  __shared__ float sredB[8];
  __shared__ float sredY[BPB][2];

  const int tid  = threadIdx.x;
  const int lane = tid & 63;
  const int wv   = tid >> 6;     // 0..15
  const int r    = tid >> 1;     // gate row 0..511
  const int hf   = tid & 1;      // K-half
  const int b0   = blockIdx.x * BPB;

  // stager threads [512,768): bg = sgBg, float2-slot sgMp (covers m=2*sgMp,+1)
  const bool isStager = (tid >= 512 && tid < 768);
  const int  sgI  = tid - 512;
  const int  sgBg = sgI >> 6;
  const int  sgMp = sgI & 63;

  // issue X[t=0] load early (consumed after alpha is ready)
  float2 x0 = make_float2(0.f, 0.f);
  if (isStager)
    x0 = ((const float2*)X)[(size_t)(b0 + sgBg) * 6400 + sgMp];

  // ---------------- encoder weights -> registers (bf16 packed) -------------
  // thread (r,hf) owns row r, elements [hf*64, hf*64+64): addr = tid*64
  u32 wpkH[32], wpkI[32];
  {
    const float4* wr = (const float4*)(eWhh + (size_t)tid * 64);
    #pragma unroll
    for (int i = 0; i < 16; ++i) {
      float4 v = wr[i];
      wpkH[2*i]   = pk2(v.x, v.y);
      wpkH[2*i+1] = pk2(v.z, v.w);
    }
    const float4* wi = (const float4*)(eWih + (size_t)tid * 64);
    #pragma unroll
    for (int i = 0; i < 16; ++i) {
      float4 v = wi[i];
      wpkI[2*i]   = pk2(v.x, v.y);
      wpkI[2*i+1] = pk2(v.z, v.w);
    }
  }
  float biasg = (hf == 0) ? (ebih[r] + ebhh[r]) : 0.f;
  (void)eAb;  // cancels in softmax over m

  // ---------------- alpha: softmax_m( sum_t X[b,t,m]*eAw[256+t] ) ----------
  float sval = 0.f;
  if (tid < 512) {
    const int abg = tid >> 7, am = tid & 127;
    const float* xp = X + (size_t)(b0 + abg) * 12800 + am;
    #pragma unroll 4
    for (int t = 0; t < T_; ++t) sval += xp[t * 128] * eAw[256 + t];
  }
  float mx = wmax(sval);
  if (lane == 0 && wv < 8) sredA[wv] = mx;
  __syncthreads();
  float ee = 0.f;
  if (tid < 512) {
    const int abg = tid >> 7;
    float gmax = fmaxf(sredA[2*abg], sredA[2*abg+1]);
    ee = __expf(sval - gmax);
  }
  float sm = wsum(ee);
  if (lane == 0 && wv < 8) sredB[wv] = sm;
  __syncthreads();
  if (tid < 512) {
    const int abg = tid >> 7, am = tid & 127;
    su[abg][am] = ee * rcpf_(sredB[2*abg] + sredB[2*abg+1]);
    sh[abg][am] = 0.f; sc[abg][am] = 0.f;
    shp[abg][am] = 0;  scp[abg][am] = 0;
  }
  __syncthreads();
  if (isStager) {
    float2 al = ((const float2*)su[sgBg])[sgMp];
    sxt[sgBg][sgMp] = pk2(x0.x * al.x, x0.y * al.y);
  }
  __syncthreads();

  // ---------------- encoder recurrence (2 barriers/step) -------------------
  {
    const float2* xpre = ((const float2*)X) + ((size_t)(b0 + sgBg) * 6400 + 64 + sgMp);
    for (int t = 0; t < T_; ++t) {
      float2 xvn = make_float2(0.f, 0.f);
      if (isStager && t + 1 < T_) xvn = xpre[(size_t)t * 64];  // X[., t+1, 2mp..]
      // gate matvec for 4 batches (shared weight regs)
      float gs[BPB];
      #pragma unroll
      for (int bg = 0; bg < BPB; ++bg) {
        const uint4* hr4 = (const uint4*)((const u32*)shp[bg] + hf * 32);
        const uint4* xr4 = (const uint4*)(sxt[bg] + hf * 32);
        float a0 = 0.f, a1 = 0.f, a2 = 0.f, a3 = 0.f;
        #pragma unroll
        for (int i = 0; i < 8; ++i) {
          uint4 hv = hr4[i], xv = xr4[i];
          a0 = dot2bf(wpkH[4*i+0], hv.x, a0);
          a1 = dot2bf(wpkH[4*i+1], hv.y, a1);
          a0 = dot2bf(wpkH[4*i+2], hv.z, a0);
          a1 = dot2bf(wpkH[4*i+3], hv.w, a1);
          a2 = dot2bf(wpkI[4*i+0], xv.x, a2);
          a3 = dot2bf(wpkI[4*i+1], xv.y, a3);
          a2 = dot2bf(wpkI[4*i+2], xv.z, a2);
          a3 = dot2bf(wpkI[4*i+3], xv.w, a3);
        }
        gs[bg] = biasg + (a0 + a1) + (a2 + a3);
      }
      #pragma unroll
      for (int bg = 0; bg < BPB; ++bg) {
        float g = gs[bg] + __shfl_xor(gs[bg], 1, 64);
        if (hf == 0) sg[bg][r] = g;
      }
      __syncthreads();
      if (isStager && t + 1 < T_) {
        float2 al = ((const float2*)su[sgBg])[sgMp];
        sxt[sgBg][sgMp] = pk2(xvn.x * al.x, xvn.y * al.y);
      }
      if (tid < 512) {
        const int bg = tid >> 7, j = tid & 127;
        float gi = sigm(sg[bg][j]);
        float gf = sigm(sg[bg][j + 128]);
        float gg = tanh_(sg[bg][j + 256]);
        float go = sigm(sg[bg][j + 384]);
        float c  = gf * sc[bg][j] + gi * gg;
        sc[bg][j] = c;
        float h  = go * tanh_(c);
        sh[bg][j] = h;
        u16 hb = f2bf(h);
        shp[bg][j] = hb;
        scp[bg][j] = f2bf(c);
        sXe[bg][t * 128 + j] = hb;
      }
      __syncthreads();
    }
  }

  // ---------------- decoder prologue: E1 -> registers ----------------------
  // E1[bg][t][h] = sum_k Xe[bg][t][k]*dW1[h][256+k] + db1[h]
  // compute per bg into sE1t (LDS temp), owners pull their 25 packed u32.
  const int hh  = tid & 127;
  const int grp = tid >> 7;            // 0..7
  u32 e1r[25];
  {
    u32 wtp[64];
    const float4* w4 = (const float4*)(dW1 + (size_t)hh * 384 + 256);
    #pragma unroll
    for (int i = 0; i < 32; ++i) {
      float4 v = w4[i];
      wtp[2*i]   = pk2(v.x, v.y);
      wtp[2*i+1] = pk2(v.z, v.w);
    }
    float b1v = db1[hh];
    const int ebg = tid >> 8;          // owner batch
    const int ewv = (tid >> 6) & 3;    // owner t-group
    for (int bg = 0; bg < BPB; ++bg) {
      for (int ii = 0; ii < 13; ++ii) {
        int t = grp + 8 * ii;
        if (t < T_) {
          const uint4* xe4 = (const uint4*)(sXe[bg] + t * 128);
          float a0 = 0.f, a1 = 0.f;
          #pragma unroll
          for (int k = 0; k < 16; ++k) {
            uint4 xv = xe4[k];
            a0 = dot2bf(wtp[4*k+0], xv.x, a0);
            a1 = dot2bf(wtp[4*k+1], xv.y, a1);
            a0 = dot2bf(wtp[4*k+2], xv.z, a0);
            a1 = dot2bf(wtp[4*k+3], xv.w, a1);
          }
          sE1t[t * 128 + hh] = f2bf(a0 + a1 + b1v);
        }
      }
      __syncthreads();
      if (ebg == bg) {
        #pragma unroll
        for (int i = 0; i < 25; ++i)
          e1r[i] = ((const u32*)sE1t)[(ewv * 25 + i) * 64 + lane];
      }
      __syncthreads();
    }
  }

  // ---------------- decoder weights -> registers ----------------------------
  u32 wpkD[32];                         // dWhh row r, half hf
  {
    const float4* wr = (const float4*)(dWhh + (size_t)tid * 64);
    #pragma unroll
    for (int i = 0; i < 16; ++i) {
      float4 v = wr[i];
      wpkD[2*i]   = pk2(v.x, v.y);
      wpkD[2*i+1] = pk2(v.z, v.w);
    }
  }
  // u-stage: thread (hh, grp): bgu = grp>>1, ks = grp&1 (0: d-part, 1: c-part)
  const int ubg = grp >> 1, uks = grp & 1;
  u32 wtpU[32];                         // W1[hh][ks*128 .. +128) packed
  {
    const float4* wu = (const float4*)(dW1 + (size_t)hh * 384 + uks * 128);
    #pragma unroll
    for (int i = 0; i < 16; ++i) {
      float4 v = wu[i];
      wtpU[2*i]   = pk2(v.x, v.y);
      wtpU[2*i+1] = pk2(v.z, v.w);
    }
  }
  float2 w2p  = ((const float2*)dW2)[lane];     // w2[2*lane], w2[2*lane+1]
  float biasD = (hf == 0) ? (dbih[r] + dbhh[r]) : 0.f;
  float wihj  = (hf == 0) ? dWih[r] : 0.f;
  float b2v   = db2[0];
  float fcbv  = fcb[0];
  float fcwv  = (tid < 512) ? fcW[tid & 127] : 0.f;
  if (tid < 512) {
    const int bg = tid >> 7, j = tid & 127;
    sh[bg][j] = 0.f; sc[bg][j] = 0.f; shp[bg][j] = 0; scp[bg][j] = 0;
  }
  const int s2bg = tid >> 8;           // S2 ownership (matches e1r)
  const int s2wv = (tid >> 6) & 3;
  const int s4h  = tid & 63;           // S4: h-pair index
  const int s4th = (tid >> 6) & 3;     // S4: t-quarter
  __syncthreads();

  // ---------------- decoder recurrence (7 barriers/step) --------------------
  for (int step = 0; step < T_; ++step) {
    // S0: u partials. u[bg][h] = W1d[h,:]*d[bg] + W1c[h,:]*c[bg]; split d/c.
    {
      const uint4* vp = (const uint4*)(uks ? (const u32*)scp[ubg]
                                           : (const u32*)shp[ubg]);
      float a0 = 0.f, a1 = 0.f;
      #pragma unroll
      for (int i = 0; i < 8; ++i) {
        uint4 v = vp[i];
        a0 = dot2bf(wtpU[4*i+0], v.x, a0);
        a1 = dot2bf(wtpU[4*i+1], v.y, a1);
        a0 = dot2bf(wtpU[4*i+2], v.z, a0);
        a1 = dot2bf(wtpU[4*i+3], v.w, a1);
      }
      spart[grp * 128 + hh] = a0 + a1;
    }
    __syncthreads();
    // S2: scores via register-resident E1 (u read once per thread)
    {
      float2 ua = ((const float2*)spart)[(2*s2bg) * 64 + lane];
      float2 ub = ((const float2*)spart)[(2*s2bg+1) * 64 + lane];
      float u0 = ua.x + ub.x, u1 = ua.y + ub.y;
      #pragma unroll
      for (int i = 0; i < 25; ++i) {
        float e0, e1; unpk(e1r[i], e0, e1);
        float v = w2p.x * ptanh(e0 + u0) + w2p.y * ptanh(e1 + u1);
        v = wsum(v);
        if (lane == 0) sscore[s2bg][s2wv * 25 + i] = v + b2v;
      }
    }
    __syncthreads();
    // S3: softmax over t (wave w handles batch w)
    if (wv < BPB) {
      float s0 = sscore[wv][lane];
      float s1 = (lane < 36) ? sscore[wv][64 + lane] : -3.0e38f;
      float m  = wmax(fmaxf(s0, s1));
      float E0 = __expf(s0 - m);
      float E1v = (lane < 36) ? __expf(s1 - m) : 0.f;
      float s  = wsum(E0 + E1v);
      float iv = rcpf_(s);
      sscore[wv][lane] = E0 * iv;
      if (lane < 36) sscore[wv][64 + lane] = E1v * iv;
    }
    __syncthreads();
    // S4: ctx partials: thread (bg, t-quarter, h-pair), u32 Xe reads
    {
      const u32* xe32 = (const u32*)sXe[s2bg];
      float pc0 = 0.f, pc1 = 0.f;
      #pragma unroll
      for (int i = 0; i < 25; ++i) {
        int t = s4th * 25 + i;
        float bt = sscore[s2bg][t];
        float xl, xh; unpk(xe32[t * 64 + s4h], xl, xh);
        pc0 += bt * xl; pc1 += bt * xh;
      }
      ((float2*)spart)[s2bg * 256 + s4th * 64 + s4h] = make_float2(pc0, pc1);
    }
    __syncthreads();
    // S5: ctx finalize + y_tilde partial
    {
      float v = 0.f;
      if (tid < 512) {
        const int bg = tid >> 7, h = tid & 127;
        float cx = spart[bg*512 + h] + spart[bg*512 + 128 + h]
                 + spart[bg*512 + 256 + h] + spart[bg*512 + 384 + h];
        sctx[bg][h] = cx;
        v = fcwv * cx;
      }
      v = wsum(v);
      if (tid < 512 && lane == 0) sredY[tid >> 7][(tid >> 6) & 1] = v;
    }
    __syncthreads();
    // S6: gates for 4 batches
    {
      float gs[BPB];
      #pragma unroll
      for (int bg = 0; bg < BPB; ++bg) {
        const uint4* hr4 = (const uint4*)((const u32*)shp[bg] + hf * 32);
        float a0 = (hf == 0)
                 ? biasD + wihj * (sredY[bg][0] + sredY[bg][1] + fcbv) : 0.f;
        float a1 = 0.f;
        #pragma unroll
        for (int i = 0; i < 8; ++i) {
          uint4 hv = hr4[i];
          a0 = dot2bf(wpkD[4*i+0], hv.x, a0);
          a1 = dot2bf(wpkD[4*i+1], hv.y, a1);
          a0 = dot2bf(wpkD[4*i+2], hv.z, a0);
          a1 = dot2bf(wpkD[4*i+3], hv.w, a1);
        }
        gs[bg] = a0 + a1;
      }
      #pragma unroll
      for (int bg = 0; bg < BPB; ++bg) {
        float g = gs[bg] + __shfl_xor(gs[bg], 1, 64);
        if (hf == 0) sg[bg][r] = g;
      }
    }
    __syncthreads();
    // S7: pointwise LSTM (all 4 batches at once)
    if (tid < 512) {
      const int bg = tid >> 7, j = tid & 127;
      float gi = sigm(sg[bg][j]);
      float gf = sigm(sg[bg][j + 128]);
      float gg = tanh_(sg[bg][j + 256]);
      float go = sigm(sg[bg][j + 384]);
      float c  = gf * sc[bg][j] + gi * gg;
      sc[bg][j] = c;
      float d  = go * tanh_(c);
      sh[bg][j] = d;
      shp[bg][j] = f2bf(d);
      scp[bg][j] = f2bf(c);
    }
    __syncthreads();
  }

  // ---------------- head: out = [d, ctx] @ fcfW^T + fcfb -------------------
  if (tid < BPB * C_) {
    const int bg = tid >> 5, cls = tid & 31;
    float acc = fcfb[cls];
    const float* w = fcfW + (size_t)cls * 256;
    #pragma unroll 8
    for (int k = 0; k < 128; ++k)
      acc += w[k] * sh[bg][k] + w[128 + k] * sctx[bg][k];
    out[(size_t)(b0 + bg) * C_ + cls] = acc;
  }
}

extern "C" void kernel_launch(void* const* d_in, const int* in_sizes, int n_in,
                              void* d_out, int out_size, void* d_ws, size_t ws_size,
                              hipStream_t stream) {
  (void)n_in; (void)out_size; (void)d_ws; (void)ws_size;
  const float* X    = (const float*)d_in[0];
  const float* eWih = (const float*)d_in[1];
  const float* eWhh = (const float*)d_in[2];
  const float* ebih = (const float*)d_in[3];
  const float* ebhh = (const float*)d_in[4];
  const float* eAw  = (const float*)d_in[5];
  const float* eAb  = (const float*)d_in[6];
  const float* dW1  = (const float*)d_in[7];
  const float* db1  = (const float*)d_in[8];
  const float* dW2  = (const float*)d_in[9];
  const float* db2  = (const float*)d_in[10];
  const float* dWih = (const float*)d_in[11];
  const float* dWhh = (const float*)d_in[12];
  const float* dbih = (const float*)d_in[13];
  const float* dbhh = (const float*)d_in[14];
  const float* fcW  = (const float*)d_in[15];
  const float* fcb  = (const float*)d_in[16];
  const float* fcfW = (const float*)d_in[17];
  const float* fcfb = (const float*)d_in[18];
  float* out = (float*)d_out;

  const int B = in_sizes[0] / (T_ * 128);
  darnn_fused<<<dim3(B / BPB), dim3(NT), 0, stream>>>(
      X, eWih, eWhh, ebih, ebhh, eAw, eAb,
      dW1, db1, dW2, db2, dWih, dWhh, dbih, dbhh,
      fcW, fcb, fcfW, fcfb, out);
}

// Round 5
// 3088.458 us; speedup vs baseline: 4.5841x; 4.5841x over previous
//
#include <hip/hip_runtime.h>

// DA-RNN fused — R5. Toolchain law (R1..R4): VGPR budget = 65536/NT and no
// attribute overrides it. So: NT=512 (128 regs/thread honored, cf. R1) and
// restructure the serial loops to need <=~120 live regs:
//   * Encoder: Q[t,j] = eWih[j,:]·x_tilde[t,:] hoisted OUT of the recurrence
//     (doesn't depend on h) -> parallel prologue GEMM into global workspace
//     (bf16, producer==consumer thread). Enc step: 64-u32 Whh row only.
//   * Decoder: wpkD(64) + wtpU(32); E1 in LDS (R3-proven).
// LDS ~58 KB -> 2 blocks/CU co-resident (2 generations, latency overlap).

typedef unsigned int   u32;
typedef unsigned short u16;

#define T_ 100
#define C_ 32
#define NT 512

__device__ __forceinline__ float bf2f(u16 u) {
  union { u32 i; float f; } v; v.i = ((u32)u) << 16; return v.f;
}
__device__ __forceinline__ u16 f2bf(float f) {
  union { float f; u32 i; } v; v.f = f;
  u32 r = v.i + 0x7fffu + ((v.i >> 16) & 1u);   // RNE
  return (u16)(r >> 16);
}
__device__ __forceinline__ void unpk(u32 p, float& lo, float& hi) {
  union { u32 i; float f; } a, b;
  a.i = p << 16; b.i = p & 0xffff0000u;
  lo = a.f; hi = b.f;
}
__device__ __forceinline__ u32 pk2(float a, float b) {
  return ((u32)f2bf(b) << 16) | (u32)f2bf(a);
}

typedef __attribute__((ext_vector_type(2))) __bf16 bf16x2;

#if __has_builtin(__builtin_amdgcn_fdot2_f32_bf16)
#define HAVE_DOT2 1
#else
#define HAVE_DOT2 0
#endif

__device__ __forceinline__ float dot2bf(u32 w, u32 x, float acc) {
#if HAVE_DOT2
  return __builtin_amdgcn_fdot2_f32_bf16(__builtin_bit_cast(bf16x2, w),
                                         __builtin_bit_cast(bf16x2, x),
                                         acc, false);
#else
  float a, b, c, d;
  unpk(w, a, b); unpk(x, c, d);
  return acc + a * c + b * d;
#endif
}

#if __has_builtin(__builtin_amdgcn_rcpf)
__device__ __forceinline__ float rcpf_(float x){ return __builtin_amdgcn_rcpf(x); }
#else
__device__ __forceinline__ float rcpf_(float x){ return 1.0f / x; }
#endif
__device__ __forceinline__ float sigm(float x){ return rcpf_(1.0f + __expf(-x)); }
__device__ __forceinline__ float tanh_(float x){
  return 1.0f - 2.0f * rcpf_(1.0f + __expf(2.0f * x));
}
// S2-only poly tanh (args tiny; clamp for safety). R4-validated numerically.
__device__ __forceinline__ float ptanh(float x){
  x = fminf(1.0f, fmaxf(-1.0f, x));
  float x2 = x * x;
  float p  = fmaf(x2, 0.1333333f, -0.3333333f);
  return x * fmaf(x2, p, 1.0f);
}

__device__ __forceinline__ float wsum(float v){
  #pragma unroll
  for (int o = 32; o; o >>= 1) v += __shfl_xor(v, o, 64);
  return v;
}
__device__ __forceinline__ float wmax(float v){
  #pragma unroll
  for (int o = 32; o; o >>= 1) v = fmaxf(v, __shfl_xor(v, o, 64));
  return v;
}

template<bool UQ>
__global__ void __launch_bounds__(NT)
darnn_fused(const float* __restrict__ X,
            const float* __restrict__ eWih, const float* __restrict__ eWhh,
            const float* __restrict__ ebih, const float* __restrict__ ebhh,
            const float* __restrict__ eAw,  const float* __restrict__ eAb,
            const float* __restrict__ dW1,  const float* __restrict__ db1,
            const float* __restrict__ dW2,  const float* __restrict__ db2,
            const float* __restrict__ dWih, const float* __restrict__ dWhh,
            const float* __restrict__ dbih, const float* __restrict__ dbhh,
            const float* __restrict__ fcW,  const float* __restrict__ fcb,
            const float* __restrict__ fcfW, const float* __restrict__ fcfb,
            u16* __restrict__ qws,
            float* __restrict__ out)
{
  // LDS ~58.4 KB -> 2 blocks/CU
  __shared__ __align__(16) u16   sxh[12800];   // x_tilde (enc) -> E1 (dec)
  __shared__ __align__(16) u16   sXe[12800];   // X_enc bf16
  __shared__ __align__(16) float sg[512];      // gates
  __shared__ __align__(16) float sh[128];      // h / d fp32
  __shared__ __align__(16) float sc[128];      // c fp32
  __shared__ __align__(16) u16   shp[128];     // h/d bf16
  __shared__ __align__(16) u16   scp[128];     // c bf16
  __shared__ __align__(16) float su[128];      // alpha
  __shared__ __align__(16) float spart[512];   // u / ctx partials
  __shared__ __align__(16) float sscore[128];  // scores -> beta
  __shared__ __align__(16) float sctx[128];    // ctx
  __shared__ float sred[8];
  __shared__ float sredY[2];

  const int tid  = threadIdx.x;
  const int lane = tid & 63;
  const int wv   = tid >> 6;     // 0..7
  const int b    = blockIdx.x;
  const int hh   = tid & 127;
  const int q4   = tid >> 7;     // 0..3

  // ---------- load X -> LDS (bf16 packed) ----------
  {
    const float4* Xb4 = (const float4*)(X + (size_t)b * 12800);
    u32* dst = (u32*)sxh;
    #pragma unroll
    for (int i = 0; i < 7; ++i) {
      int idx = tid + NT * i;
      if (idx < 3200) {
        float4 v = Xb4[idx];
        dst[2*idx]   = pk2(v.x, v.y);
        dst[2*idx+1] = pk2(v.z, v.w);
      }
    }
  }
  __syncthreads();

  // ---------- alpha = softmax_m( sum_t X[t,m]*eAw[256+t] )  (h/c cancel) ----
  float sval = 0.f;
  if (tid < 128) {
    #pragma unroll 4
    for (int t = 0; t < T_; ++t)
      sval += bf2f(sxh[t * 128 + tid]) * eAw[256 + t];
  }
  float mx = wmax(sval);
  if (lane == 0 && wv < 2) sred[wv] = mx;
  __syncthreads();
  float gmax = fmaxf(sred[0], sred[1]);
  float ee = (tid < 128) ? __expf(sval - gmax) : 0.f;
  float sm = wsum(ee);
  if (lane == 0 && wv < 2) sred[2 + wv] = sm;
  __syncthreads();
  if (tid < 128) {
    su[tid] = ee * rcpf_(sred[2] + sred[3]);
    sh[tid] = 0.f; sc[tid] = 0.f; shp[tid] = 0; scp[tid] = 0;
  }
  __syncthreads();
  // fold alpha into x -> x_tilde
  {
    u32* sx32 = (u32*)sxh;
    #pragma unroll
    for (int i = 0; i < 13; ++i) {
      int p = tid + NT * i;
      if (p < 6400) {
        float lo, hi; unpk(sx32[p], lo, hi);
        int m = (2 * p) & 127;
        sx32[p] = pk2(lo * su[m], hi * su[m + 1]);
      }
    }
  }
  (void)eAb;  // cancels in softmax
  __syncthreads();

  u16* qb = UQ ? (qws + (size_t)b * (T_ * NT)) : nullptr;

  // ---------- Q GEMM: Q[t,r] = eWih[r,:]·x_tilde[t,:]  (parallel, hoisted) --
  if (UQ) {
    u32 wq[64];
    const float4* wi = (const float4*)(eWih + (size_t)tid * 128);
    #pragma unroll
    for (int i = 0; i < 32; ++i) {
      float4 v = wi[i];
      wq[2*i]   = pk2(v.x, v.y);
      wq[2*i+1] = pk2(v.z, v.w);
    }
    for (int t = 0; t < T_; ++t) {
      const uint4* xr = (const uint4*)((const u32*)sxh + t * 64);
      float a0 = 0.f, a1 = 0.f;
      #pragma unroll
      for (int k = 0; k < 16; ++k) {
        uint4 xv = xr[k];
        a0 = dot2bf(wq[4*k+0], xv.x, a0);
        a1 = dot2bf(wq[4*k+1], xv.y, a1);
        a0 = dot2bf(wq[4*k+2], xv.z, a0);
        a1 = dot2bf(wq[4*k+3], xv.w, a1);
      }
      qb[t * NT + tid] = f2bf(a0 + a1);
    }
  }

  // ---------- encoder weights (Whh row only; Wih row too if no workspace) --
  u32 wpkH[64];
  {
    const float4* wr = (const float4*)(eWhh + (size_t)tid * 128);
    #pragma unroll
    for (int i = 0; i < 32; ++i) {
      float4 v = wr[i];
      wpkH[2*i]   = pk2(v.x, v.y);
      wpkH[2*i+1] = pk2(v.z, v.w);
    }
  }
  u32 wpkI[UQ ? 1 : 64];
  if (!UQ) {
    const float4* wi = (const float4*)(eWih + (size_t)tid * 128);
    #pragma unroll
    for (int i = 0; i < 32; ++i) {
      float4 v = wi[i];
      wpkI[UQ ? 0 : 2*i]   = pk2(v.x, v.y);
      wpkI[UQ ? 0 : 2*i+1] = pk2(v.z, v.w);
    }
  }
  float biasg = ebih[tid] + ebhh[tid];

  // ---------- encoder recurrence (2 barriers/step) ----------
  u16 qcur = UQ ? qb[tid] : (u16)0;
  for (int t = 0; t < T_; ++t) {
    u16 qnext = (UQ && t + 1 < T_) ? qb[(t + 1) * NT + tid] : (u16)0;
    float a0 = biasg, a1 = 0.f, a2 = 0.f, a3 = 0.f;
    {
      const uint4* hr = (const uint4*)(const u32*)shp;
      #pragma unroll
      for (int k = 0; k < 16; ++k) {
        uint4 hv = hr[k];
        a0 = dot2bf(wpkH[4*k+0], hv.x, a0);
        a1 = dot2bf(wpkH[4*k+1], hv.y, a1);
        a2 = dot2bf(wpkH[4*k+2], hv.z, a2);
        a3 = dot2bf(wpkH[4*k+3], hv.w, a3);
      }
    }
    if (UQ) {
      a0 += bf2f(qcur);
    } else {
      const uint4* xr = (const uint4*)((const u32*)sxh + t * 64);
      #pragma unroll
      for (int k = 0; k < 16; ++k) {
        uint4 xv = xr[k];
        a0 = dot2bf(wpkI[UQ ? 0 : 4*k+0], xv.x, a0);
        a1 = dot2bf(wpkI[UQ ? 0 : 4*k+1], xv.y, a1);
        a2 = dot2bf(wpkI[UQ ? 0 : 4*k+2], xv.z, a2);
        a3 = dot2bf(wpkI[UQ ? 0 : 4*k+3], xv.w, a3);
      }
    }
    sg[tid] = (a0 + a1) + (a2 + a3);
    qcur = qnext;
    __syncthreads();
    if (tid < 128) {
      float gi = sigm(sg[tid]);
      float gf = sigm(sg[tid + 128]);
      float gg = tanh_(sg[tid + 256]);
      float go = sigm(sg[tid + 384]);
      float c  = gf * sc[tid] + gi * gg;
      sc[tid]  = c;
      float h  = go * tanh_(c);
      sh[tid]  = h;
      u16 hb = f2bf(h);
      shp[tid] = hb;
      scp[tid] = f2bf(c);
      sXe[t * 128 + tid] = hb;
    }
    __syncthreads();
  }

  // ---------- decoder prologue: E1 -> LDS (reuse sxh slab) ----------
  // E1[t][h] = sum_k Xe[t][k]*dW1[h][256+k] + db1[h]; thread (hh, q4): 25 t's
  {
    u32 wtp[64];
    const float4* w4 = (const float4*)(dW1 + (size_t)hh * 384 + 256);
    #pragma unroll
    for (int i = 0; i < 32; ++i) {
      float4 v = w4[i];
      wtp[2*i]   = pk2(v.x, v.y);
      wtp[2*i+1] = pk2(v.z, v.w);
    }
    float b1v = db1[hh];
    u16 e1out[25];
    #pragma unroll 1
    for (int i = 0; i < 25; ++i) {
      int t = q4 * 25 + i;
      const uint4* xe4 = (const uint4*)(sXe + t * 128);
      float a0 = 0.f, a1 = 0.f;
      #pragma unroll
      for (int k = 0; k < 16; ++k) {
        uint4 xv = xe4[k];
        a0 = dot2bf(wtp[4*k+0], xv.x, a0);
        a1 = dot2bf(wtp[4*k+1], xv.y, a1);
        a0 = dot2bf(wtp[4*k+2], xv.z, a0);
        a1 = dot2bf(wtp[4*k+3], xv.w, a1);
      }
      e1out[i] = f2bf(a0 + a1 + b1v);
    }
    __syncthreads();   // all x_tilde readers done (enc loop is) — safe: slab reuse
    #pragma unroll 1
    for (int i = 0; i < 25; ++i)
      sxh[(q4 * 25 + i) * 128 + hh] = e1out[i];
  }

  // ---------- decoder weights ----------
  u32 wpkD[64];
  {
    const float4* wr = (const float4*)(dWhh + (size_t)tid * 128);
    #pragma unroll
    for (int i = 0; i < 32; ++i) {
      float4 v = wr[i];
      wpkD[2*i]   = pk2(v.x, v.y);
      wpkD[2*i+1] = pk2(v.z, v.w);
    }
  }
  // u-stage: thread (hh, q4): cols [q4*64, q4*64+64) of z=[d(128); c(128)]
  u32 wtpU[32];
  {
    const float4* wu = (const float4*)(dW1 + (size_t)hh * 384 + q4 * 64);
    #pragma unroll
    for (int i = 0; i < 16; ++i) {
      float4 v = wu[i];
      wtpU[2*i]   = pk2(v.x, v.y);
      wtpU[2*i+1] = pk2(v.z, v.w);
    }
  }
  float biasD = dbih[tid] + dbhh[tid];
  float wihj  = dWih[tid];
  float w2a   = dW2[lane];
  float w2b   = dW2[lane + 64];
  float fcbv  = fcb[0];
  float fcwv  = (tid < 128) ? fcW[tid] : 0.f;
  if (tid < 128) { sh[tid] = 0.f; sc[tid] = 0.f; shp[tid] = 0; scp[tid] = 0; }
  __syncthreads();

  // ---------- decoder recurrence (7 barriers/step) ----------
  for (int step = 0; step < T_; ++step) {
    // S0: u partials over z=[d;c] cols q4*64..+64
    {
      const u32* base = (q4 < 2) ? (const u32*)shp : (const u32*)scp;
      const uint4* vp = (const uint4*)(base + (q4 & 1) * 32);
      float a0 = 0.f, a1 = 0.f;
      #pragma unroll
      for (int k = 0; k < 8; ++k) {
        uint4 v = vp[k];
        a0 = dot2bf(wtpU[4*k+0], v.x, a0);
        a1 = dot2bf(wtpU[4*k+1], v.y, a1);
        a0 = dot2bf(wtpU[4*k+2], v.z, a0);
        a1 = dot2bf(wtpU[4*k+3], v.w, a1);
      }
      spart[q4 * 128 + hh] = a0 + a1;
    }
    __syncthreads();
    // S2: scores (u-reduce inlined). score[t] = sum_h w2[h]*tanh(E1[t,h]+u[h])
    {
      float ul = spart[lane]       + spart[128 + lane]
               + spart[256 + lane] + spart[384 + lane];
      float uh = spart[64 + lane]  + spart[192 + lane]
               + spart[320 + lane] + spart[448 + lane];
      #pragma unroll 1
      for (int i = 0; i < 13; ++i) {
        int t = wv + 8 * i;
        if (t < T_) {
          float v = w2a * ptanh(bf2f(sxh[t * 128 + lane]) + ul)
                  + w2b * ptanh(bf2f(sxh[t * 128 + 64 + lane]) + uh);
          v = wsum(v);
          if (lane == 0) sscore[t] = v;   // +b2 dropped: softmax shift-invariant
        }
      }
    }
    __syncthreads();
    // S3: softmax over t (wave 0)
    if (wv == 0) {
      float s0 = sscore[lane];
      float s1 = (lane < 36) ? sscore[lane + 64] : -3.0e38f;
      float m  = wmax(fmaxf(s0, s1));
      float E0 = __expf(s0 - m);
      float E1v = (lane < 36) ? __expf(s1 - m) : 0.f;
      float s  = wsum(E0 + E1v);
      float iv = rcpf_(s);
      sscore[lane] = E0 * iv;
      if (lane < 36) sscore[lane + 64] = E1v * iv;
    }
    __syncthreads();
    // S4: ctx partials: thread (hh, q4) over t-quarter
    {
      float pc = 0.f;
      #pragma unroll
      for (int i = 0; i < 25; ++i) {
        int t = q4 * 25 + i;
        pc += sscore[t] * bf2f(sXe[t * 128 + hh]);
      }
      spart[q4 * 128 + hh] = pc;
    }
    __syncthreads();
    // S5: ctx finalize + y_tilde partial
    {
      float v = 0.f;
      if (tid < 128) {
        float cx = spart[tid] + spart[tid + 128]
                 + spart[tid + 256] + spart[tid + 384];
        sctx[tid] = cx;
        v = fcwv * cx;
      }
      v = wsum(v);
      if (lane == 0 && wv < 2) sredY[wv] = v;
    }
    __syncthreads();
    // S6: gates: g[j] = biasD + wih[j]*y + dWhh[j,:]·d
    {
      float yt = sredY[0] + sredY[1] + fcbv;
      float a0 = biasD + wihj * yt, a1 = 0.f, a2 = 0.f, a3 = 0.f;
      const uint4* hr = (const uint4*)(const u32*)shp;
      #pragma unroll
      for (int k = 0; k < 16; ++k) {
        uint4 hv = hr[k];
        a0 = dot2bf(wpkD[4*k+0], hv.x, a0);
        a1 = dot2bf(wpkD[4*k+1], hv.y, a1);
        a2 = dot2bf(wpkD[4*k+2], hv.z, a2);
        a3 = dot2bf(wpkD[4*k+3], hv.w, a3);
      }
      sg[tid] = (a0 + a1) + (a2 + a3);
    }
    __syncthreads();
    // S7: pointwise LSTM
    if (tid < 128) {
      float gi = sigm(sg[tid]);
      float gf = sigm(sg[tid + 128]);
      float gg = tanh_(sg[tid + 256]);
      float go = sigm(sg[tid + 384]);
      float c  = gf * sc[tid] + gi * gg;
      sc[tid]  = c;
      float d  = go * tanh_(c);
      sh[tid]  = d;
      shp[tid] = f2bf(d);
      scp[tid] = f2bf(c);
    }
    __syncthreads();
  }

  // ---------- head ----------
  if (tid < C_) {
    float acc = fcfb[tid];
    const float* w = fcfW + (size_t)tid * 256;
    #pragma unroll 8
    for (int k = 0; k < 128; ++k)
      acc += w[k] * sh[k] + w[128 + k] * sctx[k];
    out[(size_t)b * C_ + tid] = acc;
  }
}

extern "C" void kernel_launch(void* const* d_in, const int* in_sizes, int n_in,
                              void* d_out, int out_size, void* d_ws, size_t ws_size,
                              hipStream_t stream) {
  (void)n_in; (void)out_size;
  const float* X    = (const float*)d_in[0];
  const float* eWih = (const float*)d_in[1];
  const float* eWhh = (const float*)d_in[2];
  const float* ebih = (const float*)d_in[3];
  const float* ebhh = (const float*)d_in[4];
  const float* eAw  = (const float*)d_in[5];
  const float* eAb  = (const float*)d_in[6];
  const float* dW1  = (const float*)d_in[7];
  const float* db1  = (const float*)d_in[8];
  const float* dW2  = (const float*)d_in[9];
  const float* db2  = (const float*)d_in[10];
  const float* dWih = (const float*)d_in[11];
  const float* dWhh = (const float*)d_in[12];
  const float* dbih = (const float*)d_in[13];
  const float* dbhh = (const float*)d_in[14];
  const float* fcW  = (const float*)d_in[15];
  const float* fcb  = (const float*)d_in[16];
  const float* fcfW = (const float*)d_in[17];
  const float* fcfb = (const float*)d_in[18];
  float* out = (float*)d_out;

  const int B = in_sizes[0] / (T_ * 128);
  const size_t needQ = (size_t)B * T_ * NT * sizeof(u16);
  if (ws_size >= needQ) {
    darnn_fused<true><<<dim3(B), dim3(NT), 0, stream>>>(
        X, eWih, eWhh, ebih, ebhh, eAw, eAb,
        dW1, db1, dW2, db2, dWih, dWhh, dbih, dbhh,
        fcW, fcb, fcfW, fcfb, (u16*)d_ws, out);
  } else {
    darnn_fused<false><<<dim3(B), dim3(NT), 0, stream>>>(
        X, eWih, eWhh, ebih, ebhh, eAw, eAb,
        dW1, db1, dW2, db2, dWih, dWhh, dbih, dbhh,
        fcW, fcb, fcfW, fcfb, nullptr, out);
  }
}

// Round 7
// 3045.678 us; speedup vs baseline: 4.6485x; 1.0140x over previous
//
#include <hip/hip_runtime.h>

// DA-RNN fused — R7 = R6 with the type fix: AMDGCN builtins use __fp16
// vectors (error msg proved cvt_pkrtz exists, returns __fp16 ext_vector(2)).
// R6 theory unchanged: gfx9 v_dot2_f32_f16 via __builtin_amdgcn_fdot2 =
// 1 VALU instr / 2 MACs, fp32 accumulate; all packed storage fp16.
// Structure: NT=512 (128-reg budget honored), Q hoisted to global ws.

typedef unsigned int   u32;
typedef unsigned short u16;

#define T_ 100
#define C_ 32
#define NT 512

typedef __attribute__((ext_vector_type(2))) __fp16 h16x2;

#if __has_builtin(__builtin_amdgcn_fdot2)
#define HAVE_FDOT2 1
#else
#define HAVE_FDOT2 0
#endif

__device__ __forceinline__ u32 pkh2(float a, float b) {
#if __has_builtin(__builtin_amdgcn_cvt_pkrtz)
  h16x2 p = __builtin_amdgcn_cvt_pkrtz(a, b);
  return __builtin_bit_cast(u32, p);
#else
  union { __fp16 h[2]; u32 u; } v;
  v.h[0] = (__fp16)a; v.h[1] = (__fp16)b;
  return v.u;
#endif
}
__device__ __forceinline__ void unph(u32 p, float& lo, float& hi) {
  union { u32 u; __fp16 h[2]; } v; v.u = p;
  lo = (float)v.h[0]; hi = (float)v.h[1];
}
__device__ __forceinline__ u16 f2h(float f) {
  union { __fp16 h; u16 u; } v; v.h = (__fp16)f; return v.u;
}
__device__ __forceinline__ float h2f(u16 u) {
  union { u16 u; __fp16 h; } v; v.u = u; return (float)v.h;
}

// acc += dot2(fp16pair w, fp16pair x), fp32 accumulate — v_dot2_f32_f16
__device__ __forceinline__ float dot2h(u32 w, u32 x, float acc) {
#if HAVE_FDOT2
  return __builtin_amdgcn_fdot2(__builtin_bit_cast(h16x2, w),
                                __builtin_bit_cast(h16x2, x),
                                acc, false);
#else
  float a, b, c, d;
  unph(w, a, b); unph(x, c, d);
  return fmaf(a, c, fmaf(b, d, acc));
#endif
}

#if __has_builtin(__builtin_amdgcn_rcpf)
__device__ __forceinline__ float rcpf_(float x){ return __builtin_amdgcn_rcpf(x); }
#else
__device__ __forceinline__ float rcpf_(float x){ return 1.0f / x; }
#endif
__device__ __forceinline__ float sigm(float x){ return rcpf_(1.0f + __expf(-x)); }
__device__ __forceinline__ float tanh_(float x){
  return 1.0f - 2.0f * rcpf_(1.0f + __expf(2.0f * x));
}
// S2-only poly tanh (args tiny; clamp for safety). R4/R5-validated.
__device__ __forceinline__ float ptanh(float x){
  x = fminf(1.0f, fmaxf(-1.0f, x));
  float x2 = x * x;
  float p  = fmaf(x2, 0.1333333f, -0.3333333f);
  return x * fmaf(x2, p, 1.0f);
}

__device__ __forceinline__ float wsum(float v){
  #pragma unroll
  for (int o = 32; o; o >>= 1) v += __shfl_xor(v, o, 64);
  return v;
}
__device__ __forceinline__ float wmax(float v){
  #pragma unroll
  for (int o = 32; o; o >>= 1) v = fmaxf(v, __shfl_xor(v, o, 64));
  return v;
}

template<bool UQ>
__global__ void __launch_bounds__(NT)
darnn_fused(const float* __restrict__ X,
            const float* __restrict__ eWih, const float* __restrict__ eWhh,
            const float* __restrict__ ebih, const float* __restrict__ ebhh,
            const float* __restrict__ eAw,  const float* __restrict__ eAb,
            const float* __restrict__ dW1,  const float* __restrict__ db1,
            const float* __restrict__ dW2,  const float* __restrict__ db2,
            const float* __restrict__ dWih, const float* __restrict__ dWhh,
            const float* __restrict__ dbih, const float* __restrict__ dbhh,
            const float* __restrict__ fcW,  const float* __restrict__ fcb,
            const float* __restrict__ fcfW, const float* __restrict__ fcfb,
            u16* __restrict__ qws,
            float* __restrict__ out)
{
  // LDS ~58.4 KB
  __shared__ __align__(16) u16   sxh[12800];   // x_tilde (enc) -> E1 (dec), fp16
  __shared__ __align__(16) u16   sXe[12800];   // X_enc fp16
  __shared__ __align__(16) float sg[512];      // gates
  __shared__ __align__(16) float sh[128];      // h / d fp32
  __shared__ __align__(16) float sc[128];      // c fp32
  __shared__ __align__(16) u16   shp[128];     // h/d fp16
  __shared__ __align__(16) u16   scp[128];     // c fp16
  __shared__ __align__(16) float su[128];      // alpha
  __shared__ __align__(16) float spart[512];   // u / ctx partials
  __shared__ __align__(16) float sscore[128];  // scores -> beta
  __shared__ __align__(16) float sctx[128];    // ctx
  __shared__ float sred[8];
  __shared__ float sredY[2];

  const int tid  = threadIdx.x;
  const int lane = tid & 63;
  const int wv   = tid >> 6;     // 0..7
  const int b    = blockIdx.x;
  const int hh   = tid & 127;
  const int q4   = tid >> 7;     // 0..3

  // ---------- load X -> LDS (fp16 packed) ----------
  {
    const float4* Xb4 = (const float4*)(X + (size_t)b * 12800);
    u32* dst = (u32*)sxh;
    #pragma unroll
    for (int i = 0; i < 7; ++i) {
      int idx = tid + NT * i;
      if (idx < 3200) {
        float4 v = Xb4[idx];
        dst[2*idx]   = pkh2(v.x, v.y);
        dst[2*idx+1] = pkh2(v.z, v.w);
      }
    }
  }
  __syncthreads();

  // ---------- alpha = softmax_m( sum_t X[t,m]*eAw[256+t] )  (h/c cancel) ----
  float sval = 0.f;
  if (tid < 128) {
    #pragma unroll 4
    for (int t = 0; t < T_; ++t)
      sval += h2f(sxh[t * 128 + tid]) * eAw[256 + t];
  }
  float mx = wmax(sval);
  if (lane == 0 && wv < 2) sred[wv] = mx;
  __syncthreads();
  float gmax = fmaxf(sred[0], sred[1]);
  float ee = (tid < 128) ? __expf(sval - gmax) : 0.f;
  float sm = wsum(ee);
  if (lane == 0 && wv < 2) sred[2 + wv] = sm;
  __syncthreads();
  if (tid < 128) {
    su[tid] = ee * rcpf_(sred[2] + sred[3]);
    sh[tid] = 0.f; sc[tid] = 0.f; shp[tid] = 0; scp[tid] = 0;
  }
  __syncthreads();
  // fold alpha into x -> x_tilde
  {
    u32* sx32 = (u32*)sxh;
    #pragma unroll
    for (int i = 0; i < 13; ++i) {
      int p = tid + NT * i;
      if (p < 6400) {
        float lo, hi; unph(sx32[p], lo, hi);
        int m = (2 * p) & 127;
        sx32[p] = pkh2(lo * su[m], hi * su[m + 1]);
      }
    }
  }
  (void)eAb;  // cancels in softmax
  __syncthreads();

  u16* qb = UQ ? (qws + (size_t)b * (T_ * NT)) : nullptr;

  // ---------- Q GEMM: Q[t,r] = eWih[r,:]·x_tilde[t,:]  (parallel, hoisted) --
  if (UQ) {
    u32 wq[64];
    const float4* wi = (const float4*)(eWih + (size_t)tid * 128);
    #pragma unroll
    for (int i = 0; i < 32; ++i) {
      float4 v = wi[i];
      wq[2*i]   = pkh2(v.x, v.y);
      wq[2*i+1] = pkh2(v.z, v.w);
    }
    for (int t = 0; t < T_; ++t) {
      const uint4* xr = (const uint4*)((const u32*)sxh + t * 64);
      float a0 = 0.f, a1 = 0.f;
      #pragma unroll
      for (int k = 0; k < 16; ++k) {
        uint4 xv = xr[k];
        a0 = dot2h(wq[4*k+0], xv.x, a0);
        a1 = dot2h(wq[4*k+1], xv.y, a1);
        a0 = dot2h(wq[4*k+2], xv.z, a0);
        a1 = dot2h(wq[4*k+3], xv.w, a1);
      }
      qb[t * NT + tid] = f2h(a0 + a1);
    }
  }

  // ---------- encoder weights (Whh row only; Wih row too if no workspace) --
  u32 wpkH[64];
  {
    const float4* wr = (const float4*)(eWhh + (size_t)tid * 128);
    #pragma unroll
    for (int i = 0; i < 32; ++i) {
      float4 v = wr[i];
      wpkH[2*i]   = pkh2(v.x, v.y);
      wpkH[2*i+1] = pkh2(v.z, v.w);
    }
  }
  u32 wpkI[UQ ? 1 : 64];
  if (!UQ) {
    const float4* wi = (const float4*)(eWih + (size_t)tid * 128);
    #pragma unroll
    for (int i = 0; i < 32; ++i) {
      float4 v = wi[i];
      wpkI[UQ ? 0 : 2*i]   = pkh2(v.x, v.y);
      wpkI[UQ ? 0 : 2*i+1] = pkh2(v.z, v.w);
    }
  }
  float biasg = ebih[tid] + ebhh[tid];

  // ---------- encoder recurrence (2 barriers/step) ----------
  u16 qcur = UQ ? qb[tid] : (u16)0;
  for (int t = 0; t < T_; ++t) {
    u16 qnext = (UQ && t + 1 < T_) ? qb[(t + 1) * NT + tid] : (u16)0;
    float a0 = biasg, a1 = 0.f, a2 = 0.f, a3 = 0.f;
    {
      const uint4* hr = (const uint4*)(const u32*)shp;
      #pragma unroll
      for (int k = 0; k < 16; ++k) {
        uint4 hv = hr[k];
        a0 = dot2h(wpkH[4*k+0], hv.x, a0);
        a1 = dot2h(wpkH[4*k+1], hv.y, a1);
        a2 = dot2h(wpkH[4*k+2], hv.z, a2);
        a3 = dot2h(wpkH[4*k+3], hv.w, a3);
      }
    }
    if (UQ) {
      a0 += h2f(qcur);
    } else {
      const uint4* xr = (const uint4*)((const u32*)sxh + t * 64);
      #pragma unroll
      for (int k = 0; k < 16; ++k) {
        uint4 xv = xr[k];
        a0 = dot2h(wpkI[UQ ? 0 : 4*k+0], xv.x, a0);
        a1 = dot2h(wpkI[UQ ? 0 : 4*k+1], xv.y, a1);
        a2 = dot2h(wpkI[UQ ? 0 : 4*k+2], xv.z, a2);
        a3 = dot2h(wpkI[UQ ? 0 : 4*k+3], xv.w, a3);
      }
    }
    sg[tid] = (a0 + a1) + (a2 + a3);
    qcur = qnext;
    __syncthreads();
    if (tid < 128) {
      float gi = sigm(sg[tid]);
      float gf = sigm(sg[tid + 128]);
      float gg = tanh_(sg[tid + 256]);
      float go = sigm(sg[tid + 384]);
      float c  = gf * sc[tid] + gi * gg;
      sc[tid]  = c;
      float h  = go * tanh_(c);
      sh[tid]  = h;
      u16 hb = f2h(h);
      shp[tid] = hb;
      scp[tid] = f2h(c);
      sXe[t * 128 + tid] = hb;
    }
    __syncthreads();
  }

  // ---------- decoder prologue: E1 -> LDS (reuse sxh slab) ----------
  // E1[t][h] = sum_k Xe[t][k]*dW1[h][256+k] + db1[h]; thread (hh, q4): 25 t's
  {
    u32 wtp[64];
    const float4* w4 = (const float4*)(dW1 + (size_t)hh * 384 + 256);
    #pragma unroll
    for (int i = 0; i < 32; ++i) {
      float4 v = w4[i];
      wtp[2*i]   = pkh2(v.x, v.y);
      wtp[2*i+1] = pkh2(v.z, v.w);
    }
    float b1v = db1[hh];
    u16 e1out[25];
    #pragma unroll 1
    for (int i = 0; i < 25; ++i) {
      int t = q4 * 25 + i;
      const uint4* xe4 = (const uint4*)(sXe + t * 128);
      float a0 = 0.f, a1 = 0.f;
      #pragma unroll
      for (int k = 0; k < 16; ++k) {
        uint4 xv = xe4[k];
        a0 = dot2h(wtp[4*k+0], xv.x, a0);
        a1 = dot2h(wtp[4*k+1], xv.y, a1);
        a0 = dot2h(wtp[4*k+2], xv.z, a0);
        a1 = dot2h(wtp[4*k+3], xv.w, a1);
      }
      e1out[i] = f2h(a0 + a1 + b1v);
    }
    __syncthreads();   // enc-loop x_tilde readers done — safe slab reuse
    #pragma unroll 1
    for (int i = 0; i < 25; ++i)
      sxh[(q4 * 25 + i) * 128 + hh] = e1out[i];
  }

  // ---------- decoder weights ----------
  u32 wpkD[64];
  {
    const float4* wr = (const float4*)(dWhh + (size_t)tid * 128);
    #pragma unroll
    for (int i = 0; i < 32; ++i) {
      float4 v = wr[i];
      wpkD[2*i]   = pkh2(v.x, v.y);
      wpkD[2*i+1] = pkh2(v.z, v.w);
    }
  }
  // u-stage: thread (hh, q4): cols [q4*64, q4*64+64) of z=[d(128); c(128)]
  u32 wtpU[32];
  {
    const float4* wu = (const float4*)(dW1 + (size_t)hh * 384 + q4 * 64);
    #pragma unroll
    for (int i = 0; i < 16; ++i) {
      float4 v = wu[i];
      wtpU[2*i]   = pkh2(v.x, v.y);
      wtpU[2*i+1] = pkh2(v.z, v.w);
    }
  }
  float biasD = dbih[tid] + dbhh[tid];
  float wihj  = dWih[tid];
  float w2a   = dW2[lane];
  float w2b   = dW2[lane + 64];
  float fcbv  = fcb[0];
  float fcwv  = (tid < 128) ? fcW[tid] : 0.f;
  if (tid < 128) { sh[tid] = 0.f; sc[tid] = 0.f; shp[tid] = 0; scp[tid] = 0; }
  __syncthreads();

  // ---------- decoder recurrence (7 barriers/step) ----------
  for (int step = 0; step < T_; ++step) {
    // S0: u partials over z=[d;c] cols q4*64..+64
    {
      const u32* base = (q4 < 2) ? (const u32*)shp : (const u32*)scp;
      const uint4* vp = (const uint4*)(base + (q4 & 1) * 32);
      float a0 = 0.f, a1 = 0.f;
      #pragma unroll
      for (int k = 0; k < 8; ++k) {
        uint4 v = vp[k];
        a0 = dot2h(wtpU[4*k+0], v.x, a0);
        a1 = dot2h(wtpU[4*k+1], v.y, a1);
        a0 = dot2h(wtpU[4*k+2], v.z, a0);
        a1 = dot2h(wtpU[4*k+3], v.w, a1);
      }
      spart[q4 * 128 + hh] = a0 + a1;
    }
    __syncthreads();
    // S2: scores (u-reduce inlined). score[t] = sum_h w2[h]*tanh(E1[t,h]+u[h])
    {
      float ul = spart[lane]       + spart[128 + lane]
               + spart[256 + lane] + spart[384 + lane];
      float uh = spart[64 + lane]  + spart[192 + lane]
               + spart[320 + lane] + spart[448 + lane];
      #pragma unroll 1
      for (int i = 0; i < 13; ++i) {
        int t = wv + 8 * i;
        if (t < T_) {
          float v = w2a * ptanh(h2f(sxh[t * 128 + lane]) + ul)
                  + w2b * ptanh(h2f(sxh[t * 128 + 64 + lane]) + uh);
          v = wsum(v);
          if (lane == 0) sscore[t] = v;   // +b2 dropped: softmax shift-invariant
        }
      }
    }
    __syncthreads();
    // S3: softmax over t (wave 0)
    if (wv == 0) {
      float s0 = sscore[lane];
      float s1 = (lane < 36) ? sscore[lane + 64] : -3.0e38f;
      float m  = wmax(fmaxf(s0, s1));
      float E0 = __expf(s0 - m);
      float E1v = (lane < 36) ? __expf(s1 - m) : 0.f;
      float s  = wsum(E0 + E1v);
      float iv = rcpf_(s);
      sscore[lane] = E0 * iv;
      if (lane < 36) sscore[lane + 64] = E1v * iv;
    }
    __syncthreads();
    // S4: ctx partials: thread (hh, q4) over t-quarter
    {
      float pc = 0.f;
      #pragma unroll
      for (int i = 0; i < 25; ++i) {
        int t = q4 * 25 + i;
        pc += sscore[t] * h2f(sXe[t * 128 + hh]);
      }
      spart[q4 * 128 + hh] = pc;
    }
    __syncthreads();
    // S5: ctx finalize + y_tilde partial
    {
      float v = 0.f;
      if (tid < 128) {
        float cx = spart[tid] + spart[tid + 128]
                 + spart[tid + 256] + spart[tid + 384];
        sctx[tid] = cx;
        v = fcwv * cx;
      }
      v = wsum(v);
      if (lane == 0 && wv < 2) sredY[wv] = v;
    }
    __syncthreads();
    // S6: gates: g[j] = biasD + wih[j]*y + dWhh[j,:]·d
    {
      float yt = sredY[0] + sredY[1] + fcbv;
      float a0 = biasD + wihj * yt, a1 = 0.f, a2 = 0.f, a3 = 0.f;
      const uint4* hr = (const uint4*)(const u32*)shp;
      #pragma unroll
      for (int k = 0; k < 16; ++k) {
        uint4 hv = hr[k];
        a0 = dot2h(wpkD[4*k+0], hv.x, a0);
        a1 = dot2h(wpkD[4*k+1], hv.y, a1);
        a2 = dot2h(wpkD[4*k+2], hv.z, a2);
        a3 = dot2h(wpkD[4*k+3], hv.w, a3);
      }
      sg[tid] = (a0 + a1) + (a2 + a3);
    }
    __syncthreads();
    // S7: pointwise LSTM
    if (tid < 128) {
      float gi = sigm(sg[tid]);
      float gf = sigm(sg[tid + 128]);
      float gg = tanh_(sg[tid + 256]);
      float go = sigm(sg[tid + 384]);
      float c  = gf * sc[tid] + gi * gg;
      sc[tid]  = c;
      float d  = go * tanh_(c);
      sh[tid]  = d;
      shp[tid] = f2h(d);
      scp[tid] = f2h(c);
    }
    __syncthreads();
  }

  // ---------- head ----------
  if (tid < C_) {
    float acc = fcfb[tid];
    const float* w = fcfW + (size_t)tid * 256;
    #pragma unroll 8
    for (int k = 0; k < 128; ++k)
      acc += w[k] * sh[k] + w[128 + k] * sctx[k];
    out[(size_t)b * C_ + tid] = acc;
  }
}

extern "C" void kernel_launch(void* const* d_in, const int* in_sizes, int n_in,
                              void* d_out, int out_size, void* d_ws, size_t ws_size,
                              hipStream_t stream) {
  (void)n_in; (void)out_size;
  const float* X    = (const float*)d_in[0];
  const float* eWih = (const float*)d_in[1];
  const float* eWhh = (const float*)d_in[2];
  const float* ebih = (const float*)d_in[3];
  const float* ebhh = (const float*)d_in[4];
  const float* eAw  = (const float*)d_in[5];
  const float* eAb  = (const float*)d_in[6];
  const float* dW1  = (const float*)d_in[7];
  const float* db1  = (const float*)d_in[8];
  const float* dW2  = (const float*)d_in[9];
  const float* db2  = (const float*)d_in[10];
  const float* dWih = (const float*)d_in[11];
  const float* dWhh = (const float*)d_in[12];
  const float* dbih = (const float*)d_in[13];
  const float* dbhh = (const float*)d_in[14];
  const float* fcW  = (const float*)d_in[15];
  const float* fcb  = (const float*)d_in[16];
  const float* fcfW = (const float*)d_in[17];
  const float* fcfb = (const float*)d_in[18];
  float* out = (float*)d_out;

  const int B = in_sizes[0] / (T_ * 128);
  const size_t needQ = (size_t)B * T_ * NT * sizeof(u16);
  if (ws_size >= needQ) {
    darnn_fused<true><<<dim3(B), dim3(NT), 0, stream>>>(
        X, eWih, eWhh, ebih, ebhh, eAw, eAb,
        dW1, db1, dW2, db2, dWih, dWhh, dbih, dbhh,
        fcW, fcb, fcfW, fcfb, (u16*)d_ws, out);
  } else {
    darnn_fused<false><<<dim3(B), dim3(NT), 0, stream>>>(
        X, eWih, eWhh, ebih, ebhh, eAw, eAb,
        dW1, db1, dW2, db2, dWih, dWhh, dbih, dbhh,
        fcW, fcb, fcfW, fcfb, nullptr, out);
  }
}

// Round 8
// 1318.732 us; speedup vs baseline: 10.7359x; 2.3096x over previous
//
#include <hip/hip_runtime.h>

// DA-RNN fused — R8: one-generation restructure.
//  * 4 batches/block (grid 256 = 1 generation; R7 ran 4). Weights batch-shared
//    in regs: dec loop wpkD[64]+wtpU[32] ~ 96 < 128 budget (NT=512 law).
//  * ye-trick: y = sum_t beta[t]*ye[t] + fcb with ye[t]=fcW.Xe[t] precomputed
//    -> ctx/y stages removed from the loop; ctx materialized once post-loop.
//  * Dec step = 5 barriers (was 7); softmax+y computed wave-redundantly
//    (no shuffle-chain stage S2 of old design; scores via (t,quad) partials).
//  * Xe shares the Q workspace slab (Xe[t] overwrites Q[t][0:128) after Q[t]
//    consumed; barrier-ordered) -> ws need unchanged = 104.9 MB (proven).
//  * E1 fp16 in LDS with row stride 132 u16 (8B-aligned, 4-way-bank b64 reads).

typedef unsigned int   u32;
typedef unsigned short u16;

#define T_  100
#define C_  32
#define NT  512
#define BPB 4
#define TS  132
#define QS  (T_ * NT)

typedef __attribute__((ext_vector_type(2))) __fp16 h16x2;

#if __has_builtin(__builtin_amdgcn_fdot2)
#define HAVE_FDOT2 1
#else
#define HAVE_FDOT2 0
#endif

__device__ __forceinline__ u32 pkh2(float a, float b) {
#if __has_builtin(__builtin_amdgcn_cvt_pkrtz)
  h16x2 p = __builtin_amdgcn_cvt_pkrtz(a, b);
  return __builtin_bit_cast(u32, p);
#else
  union { __fp16 h[2]; u32 u; } v;
  v.h[0] = (__fp16)a; v.h[1] = (__fp16)b;
  return v.u;
#endif
}
__device__ __forceinline__ void unph(u32 p, float& lo, float& hi) {
  union { u32 u; __fp16 h[2]; } v; v.u = p;
  lo = (float)v.h[0]; hi = (float)v.h[1];
}
__device__ __forceinline__ u16 f2h(float f) {
  union { __fp16 h; u16 u; } v; v.h = (__fp16)f; return v.u;
}
__device__ __forceinline__ float h2f(u16 u) {
  union { u16 u; __fp16 h; } v; v.u = u; return (float)v.h;
}
__device__ __forceinline__ float dot2h(u32 w, u32 x, float acc) {
#if HAVE_FDOT2
  return __builtin_amdgcn_fdot2(__builtin_bit_cast(h16x2, w),
                                __builtin_bit_cast(h16x2, x),
                                acc, false);
#else
  float a, b, c, d;
  unph(w, a, b); unph(x, c, d);
  return fmaf(a, c, fmaf(b, d, acc));
#endif
}

#if __has_builtin(__builtin_amdgcn_rcpf)
__device__ __forceinline__ float rcpf_(float x){ return __builtin_amdgcn_rcpf(x); }
#else
__device__ __forceinline__ float rcpf_(float x){ return 1.0f / x; }
#endif
__device__ __forceinline__ float sigm(float x){ return rcpf_(1.0f + __expf(-x)); }
__device__ __forceinline__ float tanh_(float x){
  return 1.0f - 2.0f * rcpf_(1.0f + __expf(2.0f * x));
}
__device__ __forceinline__ float ptanh(float x){
  x = fminf(1.0f, fmaxf(-1.0f, x));
  float x2 = x * x;
  float p  = fmaf(x2, 0.1333333f, -0.3333333f);
  return x * fmaf(x2, p, 1.0f);
}
__device__ __forceinline__ float wsum(float v){
  #pragma unroll
  for (int o = 32; o; o >>= 1) v += __shfl_xor(v, o, 64);
  return v;
}

// ============================ fast kernel (4 batches/block) =================
__global__ void __launch_bounds__(NT)
darnn4(const float* __restrict__ X,
       const float* __restrict__ eWih, const float* __restrict__ eWhh,
       const float* __restrict__ ebih, const float* __restrict__ ebhh,
       const float* __restrict__ eAw,  const float* __restrict__ eAb,
       const float* __restrict__ dW1,  const float* __restrict__ db1,
       const float* __restrict__ dW2,  const float* __restrict__ db2,
       const float* __restrict__ dWih, const float* __restrict__ dWhh,
       const float* __restrict__ dbih, const float* __restrict__ dbhh,
       const float* __restrict__ fcW,  const float* __restrict__ fcb,
       const float* __restrict__ fcfW, const float* __restrict__ fcfb,
       u16* __restrict__ qws,
       float* __restrict__ out)
{
  // LDS ~129.7 KB
  __shared__ __align__(16) u16   sE1[BPB][T_ * TS];  // x_tilde -> E1   105600
  __shared__ __align__(16) float sg[BPB][512];       //                  8192
  __shared__ __align__(16) float sh[BPB][128];       // h/d fp32         2048
  __shared__ __align__(16) float sc[BPB][128];       // c fp32           2048
  __shared__ __align__(16) u16   shp[BPB][128];      // h/d fp16         1024
  __shared__ __align__(16) u16   scp[BPB][128];      // c fp16           1024
  __shared__ __align__(16) float su[BPB][128];       // u / ctx          2048
  __shared__ __align__(16) float spart[BPB][512];    // partials         8192
  __shared__ __align__(16) float sye[BPB][128];      // ye -> beta       2048
  __shared__ __align__(16) float sw2[128];           //                   512
  __shared__ float sred[16];

  const int tid  = threadIdx.x;
  const int lane = tid & 63;
  const int wv   = tid >> 6;     // 0..7
  const int hh   = tid & 127;
  const int q4   = tid >> 7;     // 0..3
  const int b0   = blockIdx.x * BPB;

  (void)eAb; (void)db2;          // cancel under softmax shift-invariance

  if (tid < 128) sw2[tid] = dW2[tid];

  // ---------- alpha (no max-sub; h/c terms cancel) + x_tilde ----------
  {
    const float* xp = X + (size_t)(b0 + q4) * 12800 + hh;
    float sval = 0.f;
    #pragma unroll 4
    for (int t = 0; t < T_; ++t) sval += xp[t * 128] * eAw[256 + t];
    float e = __expf(sval);
    float s = wsum(e);
    if (lane == 0) sred[wv] = s;
    __syncthreads();
    float al = e * rcpf_(sred[q4 * 2] + sred[q4 * 2 + 1]);
    #pragma unroll 4
    for (int t = 0; t < T_; ++t)
      sE1[q4][t * TS + hh] = f2h(al * xp[t * 128]);
    sh[q4][hh] = 0.f; sc[q4][hh] = 0.f; shp[q4][hh] = 0; scp[q4][hh] = 0;
  }
  __syncthreads();

  // ---------- Q GEMM: Q[b][t][r] = eWih[r,:]·x_tilde  (self-produced) ----
  {
    u32 wq[64];
    const float4* wi = (const float4*)(eWih + (size_t)tid * 128);
    #pragma unroll
    for (int i = 0; i < 32; ++i) {
      float4 v = wi[i];
      wq[2*i]   = pkh2(v.x, v.y);
      wq[2*i+1] = pkh2(v.z, v.w);
    }
    #pragma unroll 1
    for (int bg = 0; bg < BPB; ++bg) {
      u16* qb = qws + (size_t)(b0 + bg) * QS;
      #pragma unroll 1
      for (int t = 0; t < T_; ++t) {
        const uint2* xr = (const uint2*)(&sE1[bg][t * TS]);
        float a0 = 0.f, a1 = 0.f;
        #pragma unroll
        for (int k = 0; k < 16; ++k) {
          uint2 xv = xr[k];
          a0 = dot2h(wq[2*k],   xv.x, a0);
          a1 = dot2h(wq[2*k+1], xv.y, a1);
        }
        qb[t * NT + tid] = f2h(a0 + a1);
      }
    }
  }

  // ---------- encoder (2 barriers/step) ----------
  {
    u32 wpkH[64];
    const float4* wr = (const float4*)(eWhh + (size_t)tid * 128);
    #pragma unroll
    for (int i = 0; i < 32; ++i) {
      float4 v = wr[i];
      wpkH[2*i]   = pkh2(v.x, v.y);
      wpkH[2*i+1] = pkh2(v.z, v.w);
    }
    float biasg = ebih[tid] + ebhh[tid];

    u16 qc[BPB];
    #pragma unroll
    for (int bg = 0; bg < BPB; ++bg)
      qc[bg] = qws[(size_t)(b0 + bg) * QS + tid];

    for (int t = 0; t < T_; ++t) {
      u16 qn[BPB];
      #pragma unroll
      for (int bg = 0; bg < BPB; ++bg)
        qn[bg] = (t + 1 < T_) ? qws[(size_t)(b0 + bg) * QS + (t + 1) * NT + tid]
                              : (u16)0;
      #pragma unroll 1
      for (int bg = 0; bg < BPB; ++bg) {
        const uint4* hr = (const uint4*)(const u32*)shp[bg];
        float a0 = biasg + h2f(qc[bg]), a1 = 0.f, a2 = 0.f, a3 = 0.f;
        #pragma unroll
        for (int k = 0; k < 16; ++k) {
          uint4 hv = hr[k];
          a0 = dot2h(wpkH[4*k+0], hv.x, a0);
          a1 = dot2h(wpkH[4*k+1], hv.y, a1);
          a2 = dot2h(wpkH[4*k+2], hv.z, a2);
          a3 = dot2h(wpkH[4*k+3], hv.w, a3);
        }
        sg[bg][tid] = (a0 + a1) + (a2 + a3);
      }
      __syncthreads();
      {
        float gi = sigm(sg[q4][hh]);
        float gf = sigm(sg[q4][hh + 128]);
        float gg = tanh_(sg[q4][hh + 256]);
        float go = sigm(sg[q4][hh + 384]);
        float c  = gf * sc[q4][hh] + gi * gg;
        sc[q4][hh] = c;
        float h  = go * tanh_(c);
        sh[q4][hh] = h;
        u16 hb = f2h(h);
        shp[q4][hh] = hb;
        scp[q4][hh] = f2h(c);
        // Xe row t shares Q's slab (Q[t] already consumed; barrier-ordered)
        qws[(size_t)(b0 + q4) * QS + t * NT + hh] = hb;
      }
      __syncthreads();
      #pragma unroll
      for (int bg = 0; bg < BPB; ++bg) qc[bg] = qn[bg];
    }
  }

  // ---------- ye[t] = fcW · Xe[t]  ----------
  if (hh < T_) {
    #pragma unroll 1
    for (int bg = 0; bg < BPB; ++bg) {
      const uint2* xe = (const uint2*)(qws + (size_t)(b0 + bg) * QS
                                       + hh * NT + q4 * 32);
      const float* fw = fcW + q4 * 32;
      float a = 0.f;
      #pragma unroll
      for (int k = 0; k < 8; ++k) {
        uint2 xv = xe[k];
        float l0, l1, l2, l3;
        unph(xv.x, l0, l1); unph(xv.y, l2, l3);
        a += fw[4*k]*l0 + fw[4*k+1]*l1 + fw[4*k+2]*l2 + fw[4*k+3]*l3;
      }
      spart[bg][hh * 4 + q4] = a;
    }
  }
  __syncthreads();
  if (hh < T_) {
    float4 p = ((const float4*)spart[q4])[hh];
    sye[q4][hh] = (p.x + p.y) + (p.z + p.w);
  }
  __syncthreads();

  // ---------- E1[t][h] = dW1[h][256:384]·Xe[t] + db1[h] -> LDS ----------
  {
    u32 wtp[64];
    const float4* w4p = (const float4*)(dW1 + (size_t)hh * 384 + 256);
    #pragma unroll
    for (int i = 0; i < 32; ++i) {
      float4 v = w4p[i];
      wtp[2*i]   = pkh2(v.x, v.y);
      wtp[2*i+1] = pkh2(v.z, v.w);
    }
    float b1v = db1[hh];
    #pragma unroll 1
    for (int bg = 0; bg < BPB; ++bg) {
      #pragma unroll 1
      for (int i = 0; i < 25; ++i) {
        int t = q4 * 25 + i;
        const uint2* xe = (const uint2*)(qws + (size_t)(b0 + bg) * QS + t * NT);
        float a0 = 0.f, a1 = 0.f;
        #pragma unroll
        for (int k = 0; k < 16; ++k) {
          uint2 xv = xe[k];
          a0 = dot2h(wtp[2*k],   xv.x, a0);
          a1 = dot2h(wtp[2*k+1], xv.y, a1);
        }
        sE1[bg][t * TS + hh] = f2h(a0 + a1 + b1v);
      }
    }
  }

  // ---------- decoder weights ----------
  u32 wpkD[64];
  {
    const float4* wr = (const float4*)(dWhh + (size_t)tid * 128);
    #pragma unroll
    for (int i = 0; i < 32; ++i) {
      float4 v = wr[i];
      wpkD[2*i]   = pkh2(v.x, v.y);
      wpkD[2*i+1] = pkh2(v.z, v.w);
    }
  }
  u32 wtpU[32];   // dW1 row hh, z-cols [q4*64, q4*64+64)
  {
    const float4* wu = (const float4*)(dW1 + (size_t)hh * 384 + q4 * 64);
    #pragma unroll
    for (int i = 0; i < 16; ++i) {
      float4 v = wu[i];
      wtpU[2*i]   = pkh2(v.x, v.y);
      wtpU[2*i+1] = pkh2(v.z, v.w);
    }
  }
  float biasD = dbih[tid] + dbhh[tid];
  float wihj  = dWih[tid];
  float fcbv  = fcb[0];
  sh[q4][hh] = 0.f; sc[q4][hh] = 0.f; shp[q4][hh] = 0; scp[q4][hh] = 0;
  __syncthreads();

  // ---------- decoder (5 barriers/step) ----------
  for (int step = 0; step < T_; ++step) {
    // S0: u partials over z=[d;c] cols q4*64..+64, all batches
    #pragma unroll 1
    for (int bg = 0; bg < BPB; ++bg) {
      const u32* bs = (q4 < 2) ? (const u32*)shp[bg] : (const u32*)scp[bg];
      const uint4* vp = (const uint4*)(bs + (q4 & 1) * 32);
      float a0 = 0.f, a1 = 0.f;
      #pragma unroll
      for (int k = 0; k < 8; ++k) {
        uint4 v = vp[k];
        a0 = dot2h(wtpU[4*k+0], v.x, a0);
        a1 = dot2h(wtpU[4*k+1], v.y, a1);
        a0 = dot2h(wtpU[4*k+2], v.z, a0);
        a1 = dot2h(wtpU[4*k+3], v.w, a1);
      }
      spart[bg][q4 * 128 + hh] = a0 + a1;
    }
    __syncthreads();
    // S1: reduce u
    su[q4][hh] = spart[q4][hh] + spart[q4][128 + hh]
               + spart[q4][256 + hh] + spart[q4][384 + hh];
    __syncthreads();
    // S2: score partials: thread (t=hh<100, quad q4), 32 h each
    if (hh < T_) {
      #pragma unroll 1
      for (int bg = 0; bg < BPB; ++bg) {
        const uint2*  ep = (const uint2*)(&sE1[bg][hh * TS + q4 * 32]);
        const float4* up = (const float4*)(&su[bg][q4 * 32]);
        const float4* wp = (const float4*)(&sw2[q4 * 32]);
        float acc = 0.f;
        #pragma unroll
        for (int j = 0; j < 8; ++j) {
          uint2  e2 = ep[j];
          float4 u4 = up[j];
          float4 w4 = wp[j];
          float e0, e1, e2f, e3;
          unph(e2.x, e0, e1); unph(e2.y, e2f, e3);
          acc += w4.x * ptanh(e0  + u4.x) + w4.y * ptanh(e1 + u4.y)
               + w4.z * ptanh(e2f + u4.z) + w4.w * ptanh(e3 + u4.w);
        }
        spart[bg][hh * 4 + q4] = acc;
      }
    }
    __syncthreads();
    // S3: softmax over t + y, wave-redundant (no barrier after)
    float yv[BPB];
    #pragma unroll
    for (int bg = 0; bg < BPB; ++bg) {
      float4 p0 = ((const float4*)spart[bg])[lane];
      float e0 = __expf((p0.x + p0.y) + (p0.z + p0.w));
      float es = e0, ys = e0 * sye[bg][lane];
      if (lane < 36) {
        float4 p1 = ((const float4*)spart[bg])[64 + lane];
        float e1 = __expf((p1.x + p1.y) + (p1.z + p1.w));
        es += e1; ys += e1 * sye[bg][64 + lane];
      }
      es = wsum(es); ys = wsum(ys);
      yv[bg] = ys * rcpf_(es) + fcbv;
    }
    // S6: gates
    #pragma unroll 1
    for (int bg = 0; bg < BPB; ++bg) {
      const uint4* hr = (const uint4*)(const u32*)shp[bg];
      float a0 = biasD + wihj * yv[bg], a1 = 0.f, a2 = 0.f, a3 = 0.f;
      #pragma unroll
      for (int k = 0; k < 16; ++k) {
        uint4 hv = hr[k];
        a0 = dot2h(wpkD[4*k+0], hv.x, a0);
        a1 = dot2h(wpkD[4*k+1], hv.y, a1);
        a2 = dot2h(wpkD[4*k+2], hv.z, a2);
        a3 = dot2h(wpkD[4*k+3], hv.w, a3);
      }
      sg[bg][tid] = (a0 + a1) + (a2 + a3);
    }
    __syncthreads();
    // S7: pointwise LSTM (all 4 batches, full block)
    {
      float gi = sigm(sg[q4][hh]);
      float gf = sigm(sg[q4][hh + 128]);
      float gg = tanh_(sg[q4][hh + 256]);
      float go = sigm(sg[q4][hh + 384]);
      float c  = gf * sc[q4][hh] + gi * gg;
      sc[q4][hh] = c;
      float d  = go * tanh_(c);
      sh[q4][hh] = d;
      shp[q4][hh] = f2h(d);
      scp[q4][hh] = f2h(c);
    }
    __syncthreads();
  }

  // ---------- final beta -> ctx -> head ----------
  if (wv < BPB) {                     // wave w computes beta for batch w
    int bg = wv;
    float4 p0 = ((const float4*)spart[bg])[lane];
    float e0 = __expf((p0.x + p0.y) + (p0.z + p0.w));
    float e1 = 0.f;
    if (lane < 36) {
      float4 p1 = ((const float4*)spart[bg])[64 + lane];
      e1 = __expf((p1.x + p1.y) + (p1.z + p1.w));
    }
    float iv = rcpf_(wsum(e0 + e1));
    sye[bg][lane] = e0 * iv;          // overwrite ye with beta
    if (lane < 36) sye[bg][64 + lane] = e1 * iv;
  }
  __syncthreads();
  {
    const u16* xeb = qws + (size_t)(b0 + q4) * QS + hh;
    float cx = 0.f;
    #pragma unroll 4
    for (int t = 0; t < T_; ++t)
      cx += sye[q4][t] * h2f(xeb[t * NT]);
    su[q4][hh] = cx;                  // ctx
  }
  __syncthreads();
  if (tid < BPB * C_) {
    int bg = tid >> 5, cls = tid & 31;
    const float* w = fcfW + (size_t)cls * 256;
    float acc = fcfb[cls];
    #pragma unroll 8
    for (int k = 0; k < 128; ++k)
      acc += w[k] * sh[bg][k] + w[128 + k] * su[bg][k];
    out[(size_t)(b0 + bg) * C_ + cls] = acc;
  }
}

// ================== fallback (R7 structure, no workspace) ==================
__global__ void __launch_bounds__(NT)
darnn_fb(const float* __restrict__ X,
         const float* __restrict__ eWih, const float* __restrict__ eWhh,
         const float* __restrict__ ebih, const float* __restrict__ ebhh,
         const float* __restrict__ eAw,
         const float* __restrict__ dW1,  const float* __restrict__ db1,
         const float* __restrict__ dW2,
         const float* __restrict__ dWih, const float* __restrict__ dWhh,
         const float* __restrict__ dbih, const float* __restrict__ dbhh,
         const float* __restrict__ fcW,  const float* __restrict__ fcb,
         const float* __restrict__ fcfW, const float* __restrict__ fcfb,
         float* __restrict__ out)
{
  __shared__ __align__(16) u16   sxh[12800];
  __shared__ __align__(16) u16   sXe[12800];
  __shared__ __align__(16) float sg[512];
  __shared__ __align__(16) float sh[128];
  __shared__ __align__(16) float sc[128];
  __shared__ __align__(16) u16   shp[128];
  __shared__ __align__(16) u16   scp[128];
  __shared__ __align__(16) float su[128];
  __shared__ __align__(16) float spart[512];
  __shared__ __align__(16) float sscore[128];
  __shared__ __align__(16) float sctx[128];
  __shared__ float sred[8];
  __shared__ float sredY[2];

  const int tid  = threadIdx.x;
  const int lane = tid & 63;
  const int wv   = tid >> 6;
  const int b    = blockIdx.x;
  const int hh   = tid & 127;
  const int q4   = tid >> 7;

  {
    const float4* Xb4 = (const float4*)(X + (size_t)b * 12800);
    u32* dst = (u32*)sxh;
    #pragma unroll
    for (int i = 0; i < 7; ++i) {
      int idx = tid + NT * i;
      if (idx < 3200) {
        float4 v = Xb4[idx];
        dst[2*idx]   = pkh2(v.x, v.y);
        dst[2*idx+1] = pkh2(v.z, v.w);
      }
    }
  }
  __syncthreads();
  float sval = 0.f;
  if (tid < 128) {
    #pragma unroll 4
    for (int t = 0; t < T_; ++t)
      sval += h2f(sxh[t * 128 + tid]) * eAw[256 + t];
  }
  float ee = (tid < 128) ? __expf(sval) : 0.f;
  float sm = wsum(ee);
  if (lane == 0 && wv < 2) sred[2 + wv] = sm;
  __syncthreads();
  if (tid < 128) {
    su[tid] = ee * rcpf_(sred[2] + sred[3]);
    sh[tid] = 0.f; sc[tid] = 0.f; shp[tid] = 0; scp[tid] = 0;
  }
  __syncthreads();
  {
    u32* sx32 = (u32*)sxh;
    #pragma unroll
    for (int i = 0; i < 13; ++i) {
      int p = tid + NT * i;
      if (p < 6400) {
        float lo, hi; unph(sx32[p], lo, hi);
        int m = (2 * p) & 127;
        sx32[p] = pkh2(lo * su[m], hi * su[m + 1]);
      }
    }
  }
  __syncthreads();

  u32 wpkH[64], wpkI[64];
  {
    const float4* wr = (const float4*)(eWhh + (size_t)tid * 128);
    #pragma unroll
    for (int i = 0; i < 32; ++i) {
      float4 v = wr[i];
      wpkH[2*i] = pkh2(v.x, v.y); wpkH[2*i+1] = pkh2(v.z, v.w);
    }
    const float4* wi = (const float4*)(eWih + (size_t)tid * 128);
    #pragma unroll
    for (int i = 0; i < 32; ++i) {
      float4 v = wi[i];
      wpkI[2*i] = pkh2(v.x, v.y); wpkI[2*i+1] = pkh2(v.z, v.w);
    }
  }
  float biasg = ebih[tid] + ebhh[tid];

  for (int t = 0; t < T_; ++t) {
    float a0 = biasg, a1 = 0.f, a2 = 0.f, a3 = 0.f;
    const uint4* hr = (const uint4*)(const u32*)shp;
    #pragma unroll
    for (int k = 0; k < 16; ++k) {
      uint4 hv = hr[k];
      a0 = dot2h(wpkH[4*k+0], hv.x, a0);
      a1 = dot2h(wpkH[4*k+1], hv.y, a1);
      a2 = dot2h(wpkH[4*k+2], hv.z, a2);
      a3 = dot2h(wpkH[4*k+3], hv.w, a3);
    }
    const uint4* xr = (const uint4*)((const u32*)sxh + t * 64);
    #pragma unroll
    for (int k = 0; k < 16; ++k) {
      uint4 xv = xr[k];
      a0 = dot2h(wpkI[4*k+0], xv.x, a0);
      a1 = dot2h(wpkI[4*k+1], xv.y, a1);
      a2 = dot2h(wpkI[4*k+2], xv.z, a2);
      a3 = dot2h(wpkI[4*k+3], xv.w, a3);
    }
    sg[tid] = (a0 + a1) + (a2 + a3);
    __syncthreads();
    if (tid < 128) {
      float gi = sigm(sg[tid]);
      float gf = sigm(sg[tid + 128]);
      float gg = tanh_(sg[tid + 256]);
      float go = sigm(sg[tid + 384]);
      float c  = gf * sc[tid] + gi * gg;
      sc[tid]  = c;
      float h  = go * tanh_(c);
      sh[tid]  = h;
      u16 hb = f2h(h);
      shp[tid] = hb; scp[tid] = f2h(c);
      sXe[t * 128 + tid] = hb;
    }
    __syncthreads();
  }

  {
    u32 wtp[64];
    const float4* w4 = (const float4*)(dW1 + (size_t)hh * 384 + 256);
    #pragma unroll
    for (int i = 0; i < 32; ++i) {
      float4 v = w4[i];
      wtp[2*i] = pkh2(v.x, v.y); wtp[2*i+1] = pkh2(v.z, v.w);
    }
    float b1v = db1[hh];
    u16 e1out[25];
    #pragma unroll 1
    for (int i = 0; i < 25; ++i) {
      int t = q4 * 25 + i;
      const uint4* xe4 = (const uint4*)(sXe + t * 128);
      float a0 = 0.f, a1 = 0.f;
      #pragma unroll
      for (int k = 0; k < 16; ++k) {
        uint4 xv = xe4[k];
        a0 = dot2h(wtp[4*k+0], xv.x, a0);
        a1 = dot2h(wtp[4*k+1], xv.y, a1);
        a0 = dot2h(wtp[4*k+2], xv.z, a0);
        a1 = dot2h(wtp[4*k+3], xv.w, a1);
      }
      e1out[i] = f2h(a0 + a1 + b1v);
    }
    __syncthreads();
    #pragma unroll 1
    for (int i = 0; i < 25; ++i)
      sxh[(q4 * 25 + i) * 128 + hh] = e1out[i];
  }

  u32 wpkD[64];
  {
    const float4* wr = (const float4*)(dWhh + (size_t)tid * 128);
    #pragma unroll
    for (int i = 0; i < 32; ++i) {
      float4 v = wr[i];
      wpkD[2*i] = pkh2(v.x, v.y); wpkD[2*i+1] = pkh2(v.z, v.w);
    }
  }
  u32 wtpU[32];
  {
    const float4* wu = (const float4*)(dW1 + (size_t)hh * 384 + q4 * 64);
    #pragma unroll
    for (int i = 0; i < 16; ++i) {
      float4 v = wu[i];
      wtpU[2*i] = pkh2(v.x, v.y); wtpU[2*i+1] = pkh2(v.z, v.w);
    }
  }
  float biasD = dbih[tid] + dbhh[tid];
  float wihj  = dWih[tid];
  float w2a   = dW2[lane];
  float w2b   = dW2[lane + 64];
  float fcbv  = fcb[0];
  float fcwv  = (tid < 128) ? fcW[tid] : 0.f;
  if (tid < 128) { sh[tid] = 0.f; sc[tid] = 0.f; shp[tid] = 0; scp[tid] = 0; }
  __syncthreads();

  for (int step = 0; step < T_; ++step) {
    {
      const u32* base = (q4 < 2) ? (const u32*)shp : (const u32*)scp;
      const uint4* vp = (const uint4*)(base + (q4 & 1) * 32);
      float a0 = 0.f, a1 = 0.f;
      #pragma unroll
      for (int k = 0; k < 8; ++k) {
        uint4 v = vp[k];
        a0 = dot2h(wtpU[4*k+0], v.x, a0);
        a1 = dot2h(wtpU[4*k+1], v.y, a1);
        a0 = dot2h(wtpU[4*k+2], v.z, a0);
        a1 = dot2h(wtpU[4*k+3], v.w, a1);
      }
      spart[q4 * 128 + hh] = a0 + a1;
    }
    __syncthreads();
    {
      float ul = spart[lane] + spart[128 + lane]
               + spart[256 + lane] + spart[384 + lane];
      float uh = spart[64 + lane] + spart[192 + lane]
               + spart[320 + lane] + spart[448 + lane];
      #pragma unroll 1
      for (int i = 0; i < 13; ++i) {
        int t = wv + 8 * i;
        if (t < T_) {
          float v = w2a * ptanh(h2f(sxh[t * 128 + lane]) + ul)
                  + w2b * ptanh(h2f(sxh[t * 128 + 64 + lane]) + uh);
          v = wsum(v);
          if (lane == 0) sscore[t] = v;
        }
      }
    }
    __syncthreads();
    if (wv == 0) {
      float s0 = sscore[lane];
      float E0 = __expf(s0);
      float E1v = (lane < 36) ? __expf(sscore[lane + 64]) : 0.f;
      float s  = wsum(E0 + E1v);
      float iv = rcpf_(s);
      sscore[lane] = E0 * iv;
      if (lane < 36) sscore[lane + 64] = E1v * iv;
    }
    __syncthreads();
    {
      float pc = 0.f;
      #pragma unroll
      for (int i = 0; i < 25; ++i) {
        int t = q4 * 25 + i;
        pc += sscore[t] * h2f(sXe[t * 128 + hh]);
      }
      spart[q4 * 128 + hh] = pc;
    }
    __syncthreads();
    {
      float v = 0.f;
      if (tid < 128) {
        float cx = spart[tid] + spart[tid + 128]
                 + spart[tid + 256] + spart[tid + 384];
        sctx[tid] = cx;
        v = fcwv * cx;
      }
      v = wsum(v);
      if (lane == 0 && wv < 2) sredY[wv] = v;
    }
    __syncthreads();
    {
      float yt = sredY[0] + sredY[1] + fcbv;
      float a0 = biasD + wihj * yt, a1 = 0.f, a2 = 0.f, a3 = 0.f;
      const uint4* hr = (const uint4*)(const u32*)shp;
      #pragma unroll
      for (int k = 0; k < 16; ++k) {
        uint4 hv = hr[k];
        a0 = dot2h(wpkD[4*k+0], hv.x, a0);
        a1 = dot2h(wpkD[4*k+1], hv.y, a1);
        a2 = dot2h(wpkD[4*k+2], hv.z, a2);
        a3 = dot2h(wpkD[4*k+3], hv.w, a3);
      }
      sg[tid] = (a0 + a1) + (a2 + a3);
    }
    __syncthreads();
    if (tid < 128) {
      float gi = sigm(sg[tid]);
      float gf = sigm(sg[tid + 128]);
      float gg = tanh_(sg[tid + 256]);
      float go = sigm(sg[tid + 384]);
      float c  = gf * sc[tid] + gi * gg;
      sc[tid]  = c;
      float d  = go * tanh_(c);
      sh[tid]  = d;
      shp[tid] = f2h(d);
      scp[tid] = f2h(c);
    }
    __syncthreads();
  }

  if (tid < C_) {
    float acc = fcfb[tid];
    const float* w = fcfW + (size_t)tid * 256;
    #pragma unroll 8
    for (int k = 0; k < 128; ++k)
      acc += w[k] * sh[k] + w[128 + k] * sctx[k];
    out[(size_t)b * C_ + tid] = acc;
  }
}

extern "C" void kernel_launch(void* const* d_in, const int* in_sizes, int n_in,
                              void* d_out, int out_size, void* d_ws, size_t ws_size,
                              hipStream_t stream) {
  (void)n_in; (void)out_size;
  const float* X    = (const float*)d_in[0];
  const float* eWih = (const float*)d_in[1];
  const float* eWhh = (const float*)d_in[2];
  const float* ebih = (const float*)d_in[3];
  const float* ebhh = (const float*)d_in[4];
  const float* eAw  = (const float*)d_in[5];
  const float* eAb  = (const float*)d_in[6];
  const float* dW1  = (const float*)d_in[7];
  const float* db1  = (const float*)d_in[8];
  const float* dW2  = (const float*)d_in[9];
  const float* db2  = (const float*)d_in[10];
  const float* dWih = (const float*)d_in[11];
  const float* dWhh = (const float*)d_in[12];
  const float* dbih = (const float*)d_in[13];
  const float* dbhh = (const float*)d_in[14];
  const float* fcW  = (const float*)d_in[15];
  const float* fcb  = (const float*)d_in[16];
  const float* fcfW = (const float*)d_in[17];
  const float* fcfb = (const float*)d_in[18];
  float* out = (float*)d_out;

  const int B = in_sizes[0] / (T_ * 128);
  const size_t needQ = (size_t)B * QS * sizeof(u16);
  if (ws_size >= needQ && (B % BPB) == 0) {
    darnn4<<<dim3(B / BPB), dim3(NT), 0, stream>>>(
        X, eWih, eWhh, ebih, ebhh, eAw, eAb,
        dW1, db1, dW2, db2, dWih, dWhh, dbih, dbhh,
        fcW, fcb, fcfW, fcfb, (u16*)d_ws, out);
  } else {
    darnn_fb<<<dim3(B), dim3(NT), 0, stream>>>(
        X, eWih, eWhh, ebih, ebhh, eAw,
        dW1, db1, dW2, dWih, dWhh, dbih, dbhh,
        fcW, fcb, fcfW, fcfb, out);
  }
}